// Round 2
// baseline (517.157 us; speedup 1.0000x reference)
//
#include <hip/hip_runtime.h>

// Fused DeepSeek-PINN MoE forward on MFMA, fp32-grade via 3-way bf16 split
// (hi/mid/lo, 6 MFMA terms -> dot error ~5e-8; router top-k decisions match
// the fp32 reference).
//
// All matmuls computed swapped: D' = W^T * h^T  (A = weights, B = activations,
// token axis = lane&15).  The MFMA C/D layout (col=lane&15=token,
// row=4*(lane>>4)+reg = dim) is then IDENTICAL to the B-fragment layout of the
// next matmul (k_local = 16*(e>>2) + 4*(lane>>4) + (e&3)), so activations stay
// in registers across all 3 layers -- no LDS transpose, no shuffles.
// Weights are split+staged per-matmul into LDS by all 256 threads.

typedef __attribute__((ext_vector_type(8))) short bf16x8;   // MFMA A/B frag
typedef __attribute__((ext_vector_type(4))) float f32x4;    // MFMA C/D frag

#define MFMA16(A, B, C) __builtin_amdgcn_mfma_f32_16x16x32_bf16((A), (B), (C), 0, 0, 0)

namespace {
constexpr int D = 64, ES = 2, ER = 4, NL = 3;
constexpr int BLK = 256;           // 4 waves
constexpr int T = 2;               // 16-token tiles per wave
constexpr int TOKPB = 4 * T * 16;  // 128 tokens per block
constexpr unsigned HM = 0xFFFF0000u;

__device__ __forceinline__ float tanh_fast(float x) {
  x = fminf(15.f, fmaxf(-15.f, x));
  const float e = __expf(2.f * x);
  return 1.f - 2.f * __builtin_amdgcn_rcpf(e + 1.f);
}

// 3-way bf16 split by truncation: v = h0 + h1 + h2 + O(2^-24 |v|)
__device__ __forceinline__ void split3(float v, short& a, short& b, short& c) {
  const unsigned u0 = __builtin_bit_cast(unsigned, v);
  a = (short)(u0 >> 16);
  const float r1 = v - __builtin_bit_cast(float, u0 & HM);
  const unsigned u1 = __builtin_bit_cast(unsigned, r1);
  b = (short)(u1 >> 16);
  const float r2 = r1 - __builtin_bit_cast(float, u1 & HM);
  c = (short)(__builtin_bit_cast(unsigned, r2) >> 16);
}

// Build the 3 B-fragments of one K-step from two accumulator regs.
// B elem e = act[dim = 32*ks + 16*(e>>2) + 4g + (e&3)] = acc[2ks+(e>>2)][e&3].
__device__ __forceinline__ void build_b3(const f32x4 s0, const f32x4 s1,
                                         bf16x8& b0, bf16x8& b1, bf16x8& b2) {
  #pragma unroll
  for (int j = 0; j < 4; ++j) { short a,b,c; split3(s0[j],a,b,c); b0[j]=a;   b1[j]=b;   b2[j]=c; }
  #pragma unroll
  for (int j = 0; j < 4; ++j) { short a,b,c; split3(s1[j],a,b,c); b0[4+j]=a; b1[4+j]=b; b2[4+j]=c; }
}

// Stage one 64x64 fp32 W as 3-level bf16 A'-fragments (A' = W^T) into LDS.
// Frag f = mt*2+ks; A elem e: m = (ln&15)+16mt, k = 32ks+16(e>>2)+4(ln>>4)+(e&3).
// Same (g,e)->k_local map as build_b3 => k-pairing is consistent by construction.
__device__ __forceinline__ void stage_w(const float* __restrict__ W, bf16x8* wf, int tid) {
  #pragma unroll
  for (int rep = 0; rep < 2; ++rep) {
    const int slot = tid + rep * BLK;          // 512 slots = 8 frags x 64 lanes
    const int f = slot >> 6, ln = slot & 63;
    const int mt = f >> 1, ks = f & 1;
    const int m  = (ln & 15) + (mt << 4);
    const int kb = (ks << 5) + ((ln >> 4) << 2);
    float v[8];
    #pragma unroll
    for (int e = 0; e < 8; ++e) {
      const int k = kb + ((e >> 2) << 4) + (e & 3);
      v[e] = W[k * D + m];
    }
    bf16x8 h0, h1, h2;
    #pragma unroll
    for (int e = 0; e < 8; ++e) { short a,b,c; split3(v[e],a,b,c); h0[e]=a; h1[e]=b; h2[e]=c; }
    wf[(f*3 + 0)*64 + ln] = h0;
    wf[(f*3 + 1)*64 + ln] = h1;
    wf[(f*3 + 2)*64 + ln] = h2;
  }
}

// 6-term split matmul: acc += sum of products with combined magnitude >= 2^-18.
__device__ __forceinline__ void run_mfma6(const bf16x8* wf, int lane,
                                          const bf16x8 (&B)[3][T][2], f32x4 (&acc)[T][4]) {
  #pragma unroll
  for (int mt = 0; mt < 4; ++mt) {
    bf16x8 A0[2], A1[2], A2[2];
    #pragma unroll
    for (int ks = 0; ks < 2; ++ks) {
      const int f = mt*2 + ks;
      A0[ks] = wf[(f*3 + 0)*64 + lane];
      A1[ks] = wf[(f*3 + 1)*64 + lane];
      A2[ks] = wf[(f*3 + 2)*64 + lane];
    }
    #pragma unroll
    for (int tt = 0; tt < T; ++tt)
      #pragma unroll
      for (int ks = 0; ks < 2; ++ks) {       // 4 independent (tt,ks) chains
        f32x4 c = acc[tt][mt];
        c = MFMA16(A0[ks], B[0][tt][ks], c);
        c = MFMA16(A0[ks], B[1][tt][ks], c);
        c = MFMA16(A1[ks], B[0][tt][ks], c);
        c = MFMA16(A0[ks], B[2][tt][ks], c);
        c = MFMA16(A1[ks], B[1][tt][ks], c);
        c = MFMA16(A2[ks], B[0][tt][ks], c);
        acc[tt][mt] = c;
      }
  }
}

// One expert: stage W1, a1 = W1^T h + b1; u = we*tanh(a1); stage W2,
// moe += W2^T u + we*b2.   (we = 1 for shared experts.)
__device__ __forceinline__ void expert_pass(
    const float* __restrict__ W1, const float* __restrict__ b1,
    const float* __restrict__ W2, const float* __restrict__ b2,
    const bf16x8 (&hB)[3][T][2], const float (&wet)[T],
    f32x4 (&moe)[T][4], bf16x8* wf, int tid, int lane, int g) {
  __syncthreads();                 // previous consumers of wf are done
  stage_w(W1, wf, tid);
  __syncthreads();
  f32x4 a1[T][4];
  #pragma unroll
  for (int mt = 0; mt < 4; ++mt) {
    const f32x4 bb = *(const f32x4*)(b1 + (mt << 4) + (g << 2));
    #pragma unroll
    for (int tt = 0; tt < T; ++tt) a1[tt][mt] = bb;
  }
  run_mfma6(wf, lane, hB, a1);
  bf16x8 uB[3][T][2];
  #pragma unroll
  for (int tt = 0; tt < T; ++tt) {
    #pragma unroll
    for (int mt = 0; mt < 4; ++mt)
      #pragma unroll
      for (int r = 0; r < 4; ++r) a1[tt][mt][r] = wet[tt] * tanh_fast(a1[tt][mt][r]);
    #pragma unroll
    for (int ks = 0; ks < 2; ++ks)
      build_b3(a1[tt][2*ks], a1[tt][2*ks+1], uB[0][tt][ks], uB[1][tt][ks], uB[2][tt][ks]);
  }
  __syncthreads();
  stage_w(W2, wf, tid);
  __syncthreads();
  #pragma unroll
  for (int mt = 0; mt < 4; ++mt) {
    const f32x4 bb = *(const f32x4*)(b2 + (mt << 4) + (g << 2));
    #pragma unroll
    for (int tt = 0; tt < T; ++tt)
      #pragma unroll
      for (int r = 0; r < 4; ++r) moe[tt][mt][r] += wet[tt] * bb[r];
  }
  run_mfma6(wf, lane, uB, moe);
}
}  // namespace

__global__ __launch_bounds__(BLK, 2)
void pinn_moe_mfma(const float* __restrict__ x, const float* __restrict__ t,
                   const float* __restrict__ Win, const float* __restrict__ bin,
                   const float* __restrict__ sW1, const float* __restrict__ sb1,
                   const float* __restrict__ sW2, const float* __restrict__ sb2,
                   const float* __restrict__ rW1, const float* __restrict__ rb1,
                   const float* __restrict__ rW2, const float* __restrict__ rb2,
                   const float* __restrict__ routW, const float* __restrict__ routb,
                   const float* __restrict__ Wout, const float* __restrict__ bout,
                   float* __restrict__ out) {
  __shared__ bf16x8 wf[8 * 3 * 64];          // 24 KiB staged weight fragments
  const int tid = threadIdx.x;
  const int wid = tid >> 6, lane = tid & 63;
  const int l15 = lane & 15, g = lane >> 4;
  int tb[T];
  #pragma unroll
  for (int tt = 0; tt < T; ++tt) tb[tt] = blockIdx.x * TOKPB + wid * (T * 16) + tt * 16;

  // lane state: hacc[tt][mt][r] = h[token = tb[tt]+l15][dim = 16*mt + 4*g + r]
  f32x4 hacc[T][4];

  // ---- input layer ----
  #pragma unroll
  for (int tt = 0; tt < T; ++tt) {
    const float xv = x[tb[tt] + l15], tv = t[tb[tt] + l15];
    #pragma unroll
    for (int mt = 0; mt < 4; ++mt) {
      const f32x4 w0 = *(const f32x4*)(Win + (mt << 4) + (g << 2));
      const f32x4 w1 = *(const f32x4*)(Win + D + (mt << 4) + (g << 2));
      const f32x4 bb = *(const f32x4*)(bin + (mt << 4) + (g << 2));
      #pragma unroll
      for (int r = 0; r < 4; ++r)
        hacc[tt][mt][r] = tanh_fast(fmaf(xv, w0[r], fmaf(tv, w1[r], bb[r])));
    }
  }

  for (int l = 0; l < NL; ++l) {
    // h B-fragments: built once per layer, reused by all 6 experts' first matmul
    bf16x8 hB[3][T][2];
    #pragma unroll
    for (int tt = 0; tt < T; ++tt)
      #pragma unroll
      for (int ks = 0; ks < 2; ++ks)
        build_b3(hacc[tt][2*ks], hacc[tt][2*ks+1], hB[0][tt][ks], hB[1][tt][ks], hB[2][tt][ks]);

    f32x4 moe[T][4];
    #pragma unroll
    for (int tt = 0; tt < T; ++tt)
      #pragma unroll
      for (int mt = 0; mt < 4; ++mt)
        #pragma unroll
        for (int r = 0; r < 4; ++r) moe[tt][mt][r] = 0.f;

    // ---- shared experts ----
    const float one[T] = {1.f, 1.f};
    for (int e = 0; e < ES; ++e) {
      const size_t o = (size_t)(l * ES + e);
      expert_pass(sW1 + o*D*D, sb1 + o*D, sW2 + o*D*D, sb2 + o*D,
                  hB, one, moe, wf, tid, lane, g);
    }

    // ---- router: softmax + stable top-2 scatter mask (NOT renormalized) ----
    f32x4 wsel[T];
    {
      const float* rWp = routW + (size_t)l * D * ER;
      const f32x4 rb = *(const f32x4*)(routb + l * ER);
      #pragma unroll
      for (int tt = 0; tt < T; ++tt) {
        f32x4 lg = rb;
        #pragma unroll
        for (int mt = 0; mt < 4; ++mt)
          #pragma unroll
          for (int r = 0; r < 4; ++r) {
            const f32x4 w4 = *(const f32x4*)(rWp + ((mt << 4) + (g << 2) + r) * ER);
            const float hv = hacc[tt][mt][r];
            #pragma unroll
            for (int e = 0; e < 4; ++e) lg[e] = fmaf(hv, w4[e], lg[e]);
          }
        #pragma unroll
        for (int e = 0; e < 4; ++e) {        // reduce partials over the 4 lane-groups
          float vv = lg[e];
          vv += __shfl_xor(vv, 16);
          vv += __shfl_xor(vv, 32);
          lg[e] = vv;
        }
        const float mx = fmaxf(fmaxf(lg[0], lg[1]), fmaxf(lg[2], lg[3]));
        f32x4 p; float s = 0.f;
        #pragma unroll
        for (int e = 0; e < 4; ++e) { p[e] = __expf(lg[e] - mx); s += p[e]; }
        const float inv = 1.f / s;
        #pragma unroll
        for (int e = 0; e < 4; ++e) p[e] *= inv;
        // top-2, lax.top_k stable tie-break: rank = #{f: p_f>p_a or (== and f<a)}
        #pragma unroll
        for (int a = 0; a < 4; ++a) {
          int rank = 0;
          #pragma unroll
          for (int f2 = 0; f2 < 4; ++f2)
            if (f2 != a) rank += ((p[f2] > p[a]) || (p[f2] == p[a] && f2 < a)) ? 1 : 0;
          wsel[tt][a] = (rank < 2) ? p[a] : 0.f;
        }
      }
    }

    // ---- routed experts (dense, weighted -- matches reference) ----
    for (int e = 0; e < ER; ++e) {
      float wet[T];
      #pragma unroll
      for (int tt = 0; tt < T; ++tt) {       // uniform-e cndmask chain, no dyn index
        float w = wsel[tt][0];
        w = (e == 1) ? wsel[tt][1] : w;
        w = (e == 2) ? wsel[tt][2] : w;
        w = (e == 3) ? wsel[tt][3] : w;
        wet[tt] = w;
      }
      const size_t o = (size_t)(l * ER + e);
      expert_pass(rW1 + o*D*D, rb1 + o*D, rW2 + o*D*D, rb2 + o*D,
                  hB, wet, moe, wf, tid, lane, g);
    }

    // ---- residual + tanh ----
    #pragma unroll
    for (int tt = 0; tt < T; ++tt)
      #pragma unroll
      for (int mt = 0; mt < 4; ++mt)
        #pragma unroll
        for (int r = 0; r < 4; ++r)
          hacc[tt][mt][r] = tanh_fast(hacc[tt][mt][r] + moe[tt][mt][r]);
  }

  // ---- output layer ----
  const float bo = bout[0];
  #pragma unroll
  for (int tt = 0; tt < T; ++tt) {
    float o = 0.f;
    #pragma unroll
    for (int mt = 0; mt < 4; ++mt) {
      const f32x4 w = *(const f32x4*)(Wout + (mt << 4) + (g << 2));
      #pragma unroll
      for (int r = 0; r < 4; ++r) o = fmaf(hacc[tt][mt][r], w[r], o);
    }
    o += __shfl_xor(o, 16);
    o += __shfl_xor(o, 32);
    o += bo;
    if (g == 0) out[tb[tt] + l15] = o;       // 4 lane-groups hold identical sums
  }
}

extern "C" void kernel_launch(void* const* d_in, const int* in_sizes, int n_in,
                              void* d_out, int out_size, void* d_ws, size_t ws_size,
                              hipStream_t stream) {
  (void)n_in; (void)d_ws; (void)ws_size; (void)out_size;
  const float* x     = (const float*)d_in[0];
  const float* t     = (const float*)d_in[1];
  const float* Win   = (const float*)d_in[2];
  const float* bin   = (const float*)d_in[3];
  const float* sW1   = (const float*)d_in[4];
  const float* sb1   = (const float*)d_in[5];
  const float* sW2   = (const float*)d_in[6];
  const float* sb2   = (const float*)d_in[7];
  const float* rW1   = (const float*)d_in[8];
  const float* rb1   = (const float*)d_in[9];
  const float* rW2   = (const float*)d_in[10];
  const float* rb2   = (const float*)d_in[11];
  const float* routW = (const float*)d_in[12];
  const float* routb = (const float*)d_in[13];
  const float* Wout  = (const float*)d_in[14];
  const float* bout  = (const float*)d_in[15];
  float* out = (float*)d_out;

  const int n = in_sizes[0];                 // 262144 = 2048 * 128, no tail
  const int grid = n / TOKPB;
  pinn_moe_mfma<<<dim3(grid), dim3(BLK), 0, stream>>>(
      x, t, Win, bin, sW1, sb1, sW2, sb2, rW1, rb1, rW2, rb2,
      routW, routb, Wout, bout, out);
}

// Round 5
// 475.025 us; speedup vs baseline: 1.0887x; 1.0887x over previous
//
#include <hip/hip_runtime.h>
#include <cstdint>

// Fused DeepSeek-PINN MoE forward on MFMA, fp32-grade via 3-way bf16 split
// (6 MFMA terms). Round-5 = audited R4 + s_setprio around MFMA clusters:
//  * pre-kernel splits all 36 weight matrices ONCE into d_ws as the exact
//    LDS fragment image (removes per-block split VALU + scattered loads)
//  * main loop stages 24 KiB/matmul via global_load_lds dwordx4,
//    double-buffered, counted s_waitcnt vmcnt(6) + raw s_barrier
//    (no __syncthreads -> no vmcnt(0) drain; loads stay in flight)
//  * biases/routW/routb live in an LDS constant region (staged in prologue)
//    so the ONLY in-loop vmem ops are the 6 counted stage loads per wave.
//  * s_setprio(1) around run_mfma6 (T5): waves sit at different pipeline
//    phases -> scheduler favors the MFMA-issuing wave.
//  * final s_waitcnt vmcnt(0) before kernel end (dummy wrap-stage must not
//    be in flight at s_endpgm: LDS dealloc hazard).
// Activations stay in registers across all layers (swapped-operand layout).

typedef __attribute__((ext_vector_type(8))) short bf16x8;   // MFMA A/B frag
typedef __attribute__((ext_vector_type(4))) float f32x4;    // MFMA C/D frag

#define MFMA16(A, B, C) __builtin_amdgcn_mfma_f32_16x16x32_bf16((A), (B), (C), 0, 0, 0)

namespace {
constexpr int D = 64, ES = 2, ER = 4, NL = 3;
constexpr int BLK = 256;             // 4 waves
constexpr int T = 2;                 // 16-token tiles per wave
constexpr int TOKPB = 4 * T * 16;    // 128 tokens per block
constexpr int NMAT = NL * 6 * 2;     // 36 weight matrices, canonical order
constexpr int MATB = 8 * 3 * 64;     // bf16x8 per matrix (24 KiB)
constexpr int MATBYTES = MATB * 16;  // 24576
constexpr int CST_BIAS = 0;                    // [NMAT][64] biases
constexpr int CST_RW   = NMAT * 64;            // [L][D][ER] routW (768)
constexpr int CST_RB   = CST_RW + NL * D * ER; // [L][ER] routb (12)
constexpr int CST_N    = CST_RB + 16;
constexpr unsigned HM = 0xFFFF0000u;

__device__ __forceinline__ float tanh_fast(float x) {
  x = fminf(15.f, fmaxf(-15.f, x));
  const float e = __expf(2.f * x);
  return 1.f - 2.f * __builtin_amdgcn_rcpf(e + 1.f);
}

// 3-way bf16 split by truncation: v = a + b + c + O(2^-24 |v|)
__device__ __forceinline__ void split3(float v, short& a, short& b, short& c) {
  const unsigned u0 = __builtin_bit_cast(unsigned, v);
  a = (short)(u0 >> 16);
  const float r1 = v - __builtin_bit_cast(float, u0 & HM);
  const unsigned u1 = __builtin_bit_cast(unsigned, r1);
  b = (short)(u1 >> 16);
  const float r2 = r1 - __builtin_bit_cast(float, u1 & HM);
  c = (short)(__builtin_bit_cast(unsigned, r2) >> 16);
}

// B elem e = act[dim = 32*ks + 16*(e>>2) + 4g + (e&3)] = acc[2ks+(e>>2)][e&3].
__device__ __forceinline__ void build_b3(const f32x4 s0, const f32x4 s1,
                                         bf16x8& b0, bf16x8& b1, bf16x8& b2) {
  #pragma unroll
  for (int j = 0; j < 4; ++j) { short a,b,c; split3(s0[j],a,b,c); b0[j]=a;   b1[j]=b;   b2[j]=c; }
  #pragma unroll
  for (int j = 0; j < 4; ++j) { short a,b,c; split3(s1[j],a,b,c); b0[4+j]=a; b1[4+j]=b; b2[4+j]=c; }
}

// 6-term split matmul; A-fragments read from LDS (buf = exact frag image).
__device__ __forceinline__ void run_mfma6(const bf16x8* __restrict__ wf, int lane,
                                          const bf16x8 (&B)[3][T][2], f32x4 (&acc)[T][4]) {
  __builtin_amdgcn_s_setprio(1);
  #pragma unroll
  for (int mt = 0; mt < 4; ++mt) {
    bf16x8 A0[2], A1[2], A2[2];
    #pragma unroll
    for (int ks = 0; ks < 2; ++ks) {
      const int f = mt*2 + ks;
      A0[ks] = wf[(f*3 + 0)*64 + lane];
      A1[ks] = wf[(f*3 + 1)*64 + lane];
      A2[ks] = wf[(f*3 + 2)*64 + lane];
    }
    #pragma unroll
    for (int tt = 0; tt < T; ++tt)
      #pragma unroll
      for (int ks = 0; ks < 2; ++ks) {        // 4 independent dep-chains
        f32x4 c = acc[tt][mt];
        c = MFMA16(A0[ks], B[0][tt][ks], c);
        c = MFMA16(A0[ks], B[1][tt][ks], c);
        c = MFMA16(A1[ks], B[0][tt][ks], c);
        c = MFMA16(A0[ks], B[2][tt][ks], c);
        c = MFMA16(A1[ks], B[1][tt][ks], c);
        c = MFMA16(A2[ks], B[0][tt][ks], c);
        acc[tt][mt] = c;
      }
  }
  __builtin_amdgcn_s_setprio(0);
}

typedef const __attribute__((address_space(1))) unsigned int* as1u;
typedef __attribute__((address_space(3))) unsigned int* as3u;
__device__ __forceinline__ void gld_lds16(const void* g, const void* l) {
  // async global->LDS, 16B/lane; LDS dest = wave-uniform base + lane*16 (HW);
  // global source is per-lane. flat->LDS low-32-bit truncation == addrspacecast
  // (apertures are 4GiB-aligned; LLVM lowers the cast to exactly this).
  __builtin_amdgcn_global_load_lds((as1u)(uintptr_t)g,
                                   (as3u)(unsigned int)(uintptr_t)l, 16, 0, 0);
}
}  // namespace

// ---- pre-kernel: split all weights into the LDS fragment image in d_ws ----
// mat = (l*6+e)*2 + which; e<2 shared, else routed. Frag f = mt*2+ks;
// A elem e8: m = (ln&15)+16mt, k = 32ks+16*(e8>>2)+4*(ln>>4)+(e8&3).
__global__ __launch_bounds__(256) void split_weights_k(
    const float* __restrict__ sW1, const float* __restrict__ sW2,
    const float* __restrict__ rW1, const float* __restrict__ rW2,
    bf16x8* __restrict__ wsf) {
  const int mat = blockIdx.x;
  const int l = mat / 12, r = mat % 12, e = r >> 1, wch = r & 1;
  const float* W = (e < ES) ? ((wch ? sW2 : sW1) + (size_t)(l*ES + e) * D * D)
                            : ((wch ? rW2 : rW1) + (size_t)(l*ER + (e-ES)) * D * D);
  const int tid = threadIdx.x;
  bf16x8* dst = wsf + (size_t)mat * MATB;
  #pragma unroll
  for (int rep = 0; rep < 2; ++rep) {
    const int slot = tid + rep * 256;
    const int f = slot >> 6, ln = slot & 63;
    const int mt = f >> 1, ks = f & 1;
    const int m  = (ln & 15) + (mt << 4);
    const int kb = (ks << 5) + ((ln >> 4) << 2);
    bf16x8 h0, h1, h2;
    #pragma unroll
    for (int e8 = 0; e8 < 8; ++e8) {
      const int k = kb + ((e8 >> 2) << 4) + (e8 & 3);
      short a, b, c; split3(W[k * D + m], a, b, c);
      h0[e8] = a; h1[e8] = b; h2[e8] = c;
    }
    dst[(f*3 + 0)*64 + ln] = h0;
    dst[(f*3 + 1)*64 + ln] = h1;
    dst[(f*3 + 2)*64 + ln] = h2;
  }
}

// ---- main kernel ----
#define SYNC_LGKM_BAR() do { asm volatile("s_waitcnt lgkmcnt(0)" ::: "memory"); \
                             __builtin_amdgcn_s_barrier(); } while (0)
#define WAIT6_BAR()     do { asm volatile("s_waitcnt vmcnt(6)" ::: "memory");   \
                             __builtin_amdgcn_s_barrier(); } while (0)

__global__ __launch_bounds__(BLK, 2)
void pinn_moe_mfma2(const float* __restrict__ x, const float* __restrict__ t,
                    const float* __restrict__ Win, const float* __restrict__ bin,
                    const float* __restrict__ sb1, const float* __restrict__ sb2,
                    const float* __restrict__ rb1, const float* __restrict__ rb2,
                    const float* __restrict__ routW, const float* __restrict__ routb,
                    const float* __restrict__ Wout, const float* __restrict__ bout,
                    const bf16x8* __restrict__ wsf, float* __restrict__ out) {
  __shared__ bf16x8 wfrag[2][MATB];     // 48 KiB double-buffered weight frags
  __shared__ float  cst[CST_N];         // biases + routW + routb (~12 KiB)
  const int tid = threadIdx.x, wid = tid >> 6, lane = tid & 63;
  const int l15 = lane & 15, g = lane >> 4;

  // ---- earliest: DMA mat 0 -> buf 0 (6 loads/wave, counted later) ----
  {
    const char* gb = (const char*)wsf + (size_t)0 * MATBYTES + wid * 1024 + lane * 16;
    const char* lb = (const char*)&wfrag[0][0] + wid * 1024;
    #pragma unroll
    for (int rep = 0; rep < 6; ++rep) gld_lds16(gb + rep * 4096, lb + rep * 4096);
  }

  // ---- prologue: constants -> LDS (vmem here retires before first vmcnt(6)) ----
  for (int i = tid; i < NMAT * 64; i += BLK) {
    const int mI = i >> 6, j = i & 63;
    const int ll = mI / 12, rr = mI % 12, ee = rr >> 1, ww = rr & 1;
    const float* bp = (ee < ES) ? ((ww ? sb2 : sb1) + (ll*ES + ee) * D)
                                : ((ww ? rb2 : rb1) + (ll*ER + (ee-ES)) * D);
    cst[CST_BIAS + i] = bp[j];
  }
  for (int i = tid; i < NL * D * ER; i += BLK) cst[CST_RW + i] = routW[i];
  if (tid < NL * ER) cst[CST_RB + tid] = routb[tid];

  // ---- input layer ----
  int tb[T];
  #pragma unroll
  for (int tt = 0; tt < T; ++tt) tb[tt] = blockIdx.x * TOKPB + wid * (T*16) + tt * 16;
  f32x4 hacc[T][4];   // h[token = tb[tt]+l15][dim = 16mt + 4g + r]
  #pragma unroll
  for (int tt = 0; tt < T; ++tt) {
    const float xv = x[tb[tt] + l15], tv = t[tb[tt] + l15];
    #pragma unroll
    for (int mt = 0; mt < 4; ++mt) {
      const f32x4 w0 = *(const f32x4*)(Win + (mt << 4) + (g << 2));
      const f32x4 w1 = *(const f32x4*)(Win + D + (mt << 4) + (g << 2));
      const f32x4 bb = *(const f32x4*)(bin + (mt << 4) + (g << 2));
      #pragma unroll
      for (int r = 0; r < 4; ++r)
        hacc[tt][mt][r] = tanh_fast(fmaf(xv, w0[r], fmaf(tv, w1[r], bb[r])));
    }
  }

  SYNC_LGKM_BAR();   // cst visible to all waves before router reads

  #pragma unroll 1
  for (int l = 0; l < NL; ++l) {
    // h B-fragments, reused by all 6 experts' first matmul
    bf16x8 hB[3][T][2];
    #pragma unroll
    for (int tt = 0; tt < T; ++tt)
      #pragma unroll
      for (int ks = 0; ks < 2; ++ks)
        build_b3(hacc[tt][2*ks], hacc[tt][2*ks+1], hB[0][tt][ks], hB[1][tt][ks], hB[2][tt][ks]);

    // ---- router (fp32 from hacc; routW/routb from LDS) ----
    f32x4 wsel[T];
    #pragma unroll
    for (int tt = 0; tt < T; ++tt) {
      f32x4 lg = *(const f32x4*)&cst[CST_RB + l * ER];
      #pragma unroll
      for (int mt = 0; mt < 4; ++mt)
        #pragma unroll
        for (int r = 0; r < 4; ++r) {
          const f32x4 w4 = *(const f32x4*)&cst[CST_RW + l*D*ER + ((mt<<4)+(g<<2)+r)*ER];
          const float hv = hacc[tt][mt][r];
          #pragma unroll
          for (int e = 0; e < 4; ++e) lg[e] = fmaf(hv, w4[e], lg[e]);
        }
      #pragma unroll
      for (int e = 0; e < 4; ++e) {
        float vv = lg[e];
        vv += __shfl_xor(vv, 16);
        vv += __shfl_xor(vv, 32);
        lg[e] = vv;
      }
      const float mx = fmaxf(fmaxf(lg[0], lg[1]), fmaxf(lg[2], lg[3]));
      f32x4 p; float s = 0.f;
      #pragma unroll
      for (int e = 0; e < 4; ++e) { p[e] = __expf(lg[e] - mx); s += p[e]; }
      const float inv = 1.f / s;
      #pragma unroll
      for (int e = 0; e < 4; ++e) p[e] *= inv;
      #pragma unroll
      for (int a = 0; a < 4; ++a) {          // stable top-2 (lax.top_k tie-break)
        int rank = 0;
        #pragma unroll
        for (int f2 = 0; f2 < 4; ++f2)
          if (f2 != a) rank += ((p[f2] > p[a]) || (p[f2] == p[a] && f2 < a)) ? 1 : 0;
        wsel[tt][a] = (rank < 2) ? p[a] : 0.f;
      }
    }

    f32x4 moe[T][4];
    #pragma unroll
    for (int tt = 0; tt < T; ++tt)
      #pragma unroll
      for (int mt = 0; mt < 4; ++mt)
        #pragma unroll
        for (int r = 0; r < 4; ++r) moe[tt][mt][r] = 0.f;

    #pragma unroll 1
    for (int e = 0; e < 6; ++e) {            // e<2: shared (wet=1), else routed
      const int mm = (l*6 + e) * 2;
      float wet[T];
      #pragma unroll
      for (int tt = 0; tt < T; ++tt) {
        float w = 1.f;
        if (e >= ES) {
          w = wsel[tt][0];
          w = (e == 3) ? wsel[tt][1] : w;
          w = (e == 4) ? wsel[tt][2] : w;
          w = (e == 5) ? wsel[tt][3] : w;
        }
        wet[tt] = w;
      }

      // ======== phase W1 (frags in buf0; stage W2 -> buf1) ========
      SYNC_LGKM_BAR();                       // all waves done reading buf1
      {
        const int nx = mm + 1;
        const char* gb = (const char*)wsf + (size_t)nx * MATBYTES + wid * 1024 + lane * 16;
        const char* lb = (const char*)&wfrag[1][0] + wid * 1024;
        #pragma unroll
        for (int rep = 0; rep < 6; ++rep) gld_lds16(gb + rep * 4096, lb + rep * 4096);
      }
      WAIT6_BAR();                           // buf0 (this matmul) fully staged

      f32x4 a1[T][4];
      #pragma unroll
      for (int mt = 0; mt < 4; ++mt) {
        const f32x4 bb = *(const f32x4*)&cst[CST_BIAS + mm*64 + (mt << 4) + (g << 2)];
        #pragma unroll
        for (int tt = 0; tt < T; ++tt) a1[tt][mt] = bb;
      }
      run_mfma6(&wfrag[0][0], lane, hB, a1);

      // activation: u = wet * tanh(a1), split to B-frags
      bf16x8 uB[3][T][2];
      #pragma unroll
      for (int tt = 0; tt < T; ++tt) {
        #pragma unroll
        for (int mt = 0; mt < 4; ++mt)
          #pragma unroll
          for (int r = 0; r < 4; ++r) a1[tt][mt][r] = wet[tt] * tanh_fast(a1[tt][mt][r]);
        #pragma unroll
        for (int ks = 0; ks < 2; ++ks)
          build_b3(a1[tt][2*ks], a1[tt][2*ks+1], uB[0][tt][ks], uB[1][tt][ks], uB[2][tt][ks]);
      }

      // ======== phase W2 (frags in buf1; stage next W1 -> buf0) ========
      SYNC_LGKM_BAR();                       // all waves done reading buf0
      {
        const int nx = (mm + 2 < NMAT) ? mm + 2 : 0;   // wrap: dummy, drained at end
        const char* gb = (const char*)wsf + (size_t)nx * MATBYTES + wid * 1024 + lane * 16;
        const char* lb = (const char*)&wfrag[0][0] + wid * 1024;
        #pragma unroll
        for (int rep = 0; rep < 6; ++rep) gld_lds16(gb + rep * 4096, lb + rep * 4096);
      }
      WAIT6_BAR();                           // buf1 (this matmul) fully staged

      #pragma unroll
      for (int mt = 0; mt < 4; ++mt) {
        const f32x4 bb = *(const f32x4*)&cst[CST_BIAS + (mm+1)*64 + (mt << 4) + (g << 2)];
        #pragma unroll
        for (int tt = 0; tt < T; ++tt)
          #pragma unroll
          for (int r = 0; r < 4; ++r) moe[tt][mt][r] += wet[tt] * bb[r];
      }
      run_mfma6(&wfrag[1][0], lane, uB, moe);
    }

    // ---- residual + tanh ----
    #pragma unroll
    for (int tt = 0; tt < T; ++tt)
      #pragma unroll
      for (int mt = 0; mt < 4; ++mt)
        #pragma unroll
        for (int r = 0; r < 4; ++r)
          hacc[tt][mt][r] = tanh_fast(hacc[tt][mt][r] + moe[tt][mt][r]);
  }

  // ---- output layer ----
  const float bo = bout[0];
  #pragma unroll
  for (int tt = 0; tt < T; ++tt) {
    float o = 0.f;
    #pragma unroll
    for (int mt = 0; mt < 4; ++mt) {
      const f32x4 w = *(const f32x4*)(Wout + (mt << 4) + (g << 2));
      #pragma unroll
      for (int r = 0; r < 4; ++r) o = fmaf(hacc[tt][mt][r], w[r], o);
    }
    o += __shfl_xor(o, 16);
    o += __shfl_xor(o, 32);
    o += bo;
    if (g == 0) out[tb[tt] + l15] = o;
  }

  // drain the dummy wrap-stage: no outstanding LDS-dest DMA at s_endpgm
  asm volatile("s_waitcnt vmcnt(0)" ::: "memory");
}

extern "C" void kernel_launch(void* const* d_in, const int* in_sizes, int n_in,
                              void* d_out, int out_size, void* d_ws, size_t ws_size,
                              hipStream_t stream) {
  (void)n_in; (void)ws_size; (void)out_size;
  const float* x     = (const float*)d_in[0];
  const float* t     = (const float*)d_in[1];
  const float* Win   = (const float*)d_in[2];
  const float* bin   = (const float*)d_in[3];
  const float* sW1   = (const float*)d_in[4];
  const float* sb1   = (const float*)d_in[5];
  const float* sW2   = (const float*)d_in[6];
  const float* sb2   = (const float*)d_in[7];
  const float* rW1   = (const float*)d_in[8];
  const float* rb1   = (const float*)d_in[9];
  const float* rW2   = (const float*)d_in[10];
  const float* rb2   = (const float*)d_in[11];
  const float* routW = (const float*)d_in[12];
  const float* routb = (const float*)d_in[13];
  const float* Wout  = (const float*)d_in[14];
  const float* bout  = (const float*)d_in[15];
  float* out = (float*)d_out;

  bf16x8* wsf = (bf16x8*)d_ws;   // needs NMAT*24576 = 884736 B of scratch

  split_weights_k<<<dim3(NMAT), dim3(256), 0, stream>>>(sW1, sW2, rW1, rW2, wsf);

  const int n = in_sizes[0];     // 262144 = 2048 * 128, no tail
  pinn_moe_mfma2<<<dim3(n / TOKPB), dim3(BLK), 0, stream>>>(
      x, t, Win, bin, sb1, sb2, rb1, rb2, routW, routb, Wout, bout, wsf, out);
}